// Round 12
// baseline (453.878 us; speedup 1.0000x reference)
//
#include <hip/hip_runtime.h>

// Problem constants
#define B_    8
#define H_    512
#define W_    512
#define KK_   9
#define COUT_ 3
#define HO_   510
#define WO_   510
#define PLANE_ 260100           // HO_*WO_

typedef float f2 __attribute__((ext_vector_type(2)));

__device__ __forceinline__ int iclamp(int v, int lo, int hi) {
    return v < lo ? lo : (v > hi ? hi : v);
}

// ---------- pre-pass: pack vertical row pairs ----------
// P[b][y][x] = { x[y][x], x[min(y+1,511)][x] }  (float2, 16 MiB total)
__global__ __launch_bounds__(256) void pack_pairs(
    const float* __restrict__ x, f2* __restrict__ P)
{
    const int i  = blockIdx.x * 256 + threadIdx.x;   // 8*512*512
    const int xi = i & 511;
    const int y  = (i >> 9) & 511;
    const int b  = i >> 18;
    const float* xb = x + (b << 18);
    const int y1 = y < 511 ? y + 1 : 511;
    f2 q;
    q[0] = xb[(y  << 9) + xi];
    q[1] = xb[(y1 << 9) + xi];
    P[i] = q;
}

// ---------- main kernel: two 8B gathers per bilinear sample ----------
__global__ __launch_bounds__(256, 6) void dcn_fwd_pair(
    const float* __restrict__ x,       // slow path only
    const f2*    __restrict__ P,       // [B,512,512] row pairs
    const float* __restrict__ offset,  // [B,18,510,510]
    const float* __restrict__ mask,    // [B,9,510,510]
    const float* __restrict__ weight,  // [3,1,3,3]
    const float* __restrict__ bias,    // [3]
    float* __restrict__ out)           // [B,3,510,510]
{
    // XCD affinity: b = bid & 7 -> (with round-robin dispatch) one batch per XCD;
    // gather working set = x (1 MB) + P_b (2 MB) fits the XCD's 4 MB L2.
    const int bid = blockIdx.x;        // 0 .. 8*510-1
    const int b   = bid & 7;
    const int ho  = bid >> 3;          // 0..509

    const int j   = threadIdx.x;       // 2 px each
    int wo0 = 2 * j;
    if (wo0 > WO_ - 2) wo0 = WO_ - 2;  // j=255 duplicates last pair (benign)

    const int pix = ho * WO_ + wo0;
    const float* xb = x + (b << 18);
    const f2*    Pb = P + (b << 18);
    const float* offb = offset + b * (2 * KK_ * PLANE_) + pix;
    const float* mb   = mask   + b * (KK_ * PLANE_)    + pix;

    float w0[KK_], w1[KK_], w2[KK_];
    #pragma unroll
    for (int k = 0; k < KK_; ++k) {
        w0[k] = weight[0 * KK_ + k];
        w1[k] = weight[1 * KK_ + k];
        w2[k] = weight[2 * KK_ + k];
    }
    const float b0 = bias[0], b1 = bias[1], b2 = bias[2];

    const float fho = (float)ho;
    const float fwo = (float)wo0;

    float a00 = 0.f, a01 = 0.f;
    float a10 = 0.f, a11 = 0.f;
    float a20 = 0.f, a21 = 0.f;

    #pragma unroll
    for (int kh = 0; kh < 3; ++kh) {
        #pragma unroll
        for (int kw = 0; kw < 3; ++kw) {
            const int kk = kh * 3 + kw;
            const f2 dy2 = *(const f2*)(offb + (2 * kk)     * PLANE_);
            const f2 dx2 = *(const f2*)(offb + (2 * kk + 1) * PLANE_);
            const f2 m2  = *(const f2*)(mb   +  kk          * PLANE_);

            #pragma unroll
            for (int p = 0; p < 2; ++p) {
                const float py = (fho + (float)kh) + dy2[p];
                const float px = (fwo + (float)(kw + p)) + dx2[p];

                const float y0f = floorf(py);
                const float x0f = floorf(px);
                const float ly  = py - y0f;
                const float lx  = px - x0f;

                const int iy0 = (int)y0f;
                const int ix0 = (int)x0f;

                float v00, v01, v10, v11;
                if (__builtin_expect(((unsigned)iy0 < 511u) & ((unsigned)ix0 < 511u), 1)) {
                    // all 4 corners in-image: two 8B gathers, no validity math
                    const int a = (iy0 << 9) + ix0;
                    const f2 q0 = Pb[a];        // {v00, v10}
                    const f2 q1 = Pb[a + 1];    // {v01, v11}
                    v00 = q0[0]; v10 = q0[1];
                    v01 = q1[0]; v11 = q1[1];
                } else {
                    // border/outside: full reference semantics (rare)
                    const float y1f = y0f + 1.0f, x1f = x0f + 1.0f;
                    const float vy0 = (y0f >= 0.f && y0f <= 511.f) ? 1.f : 0.f;
                    const float vy1 = (y1f >= 0.f && y1f <= 511.f) ? 1.f : 0.f;
                    const float vx0 = (x0f >= 0.f && x0f <= 511.f) ? 1.f : 0.f;
                    const float vx1 = (x1f >= 0.f && x1f <= 511.f) ? 1.f : 0.f;
                    const int yi0 = iclamp(iy0, 0, 511);
                    const int yi1 = iclamp(iy0 + 1, 0, 511);
                    const int xi0 = iclamp(ix0, 0, 511);
                    const int xi1 = iclamp(ix0 + 1, 0, 511);
                    v00 = xb[(yi0 << 9) + xi0] * (vy0 * vx0);
                    v01 = xb[(yi0 << 9) + xi1] * (vy0 * vx1);
                    v10 = xb[(yi1 << 9) + xi0] * (vy1 * vx0);
                    v11 = xb[(yi1 << 9) + xi1] * (vy1 * vx1);
                }

                const float top = fmaf(lx, v01 - v00, v00);
                const float bot = fmaf(lx, v11 - v10, v10);
                const float val = fmaf(ly, bot - top, top);
                const float s   = val * m2[p];

                if (p == 0) {
                    a00 = fmaf(w0[kk], s, a00);
                    a10 = fmaf(w1[kk], s, a10);
                    a20 = fmaf(w2[kk], s, a20);
                } else {
                    a01 = fmaf(w0[kk], s, a01);
                    a11 = fmaf(w1[kk], s, a11);
                    a21 = fmaf(w2[kk], s, a21);
                }
            }
        }
    }

    const int ob = b * (COUT_ * PLANE_) + pix;
    f2 o0 = {a00 + b0, a01 + b0};
    f2 o1 = {a10 + b1, a11 + b1};
    f2 o2 = {a20 + b2, a21 + b2};
    *(f2*)(out + ob)              = o0;
    *(f2*)(out + ob + PLANE_)     = o1;
    *(f2*)(out + ob + 2 * PLANE_) = o2;
}

// ---------- fallback (no workspace): R5-style direct-gather kernel ----------
__global__ __launch_bounds__(256) void dcn_fwd_direct(
    const float* __restrict__ x, const float* __restrict__ offset,
    const float* __restrict__ mask, const float* __restrict__ weight,
    const float* __restrict__ bias, float* __restrict__ out)
{
    const int bid = blockIdx.x;
    const int b   = bid & 7;
    const int ho  = bid >> 3;
    const int j   = threadIdx.x;
    int wo0 = 2 * j;
    if (wo0 > WO_ - 2) wo0 = WO_ - 2;

    const int pix = ho * WO_ + wo0;
    const float* xb   = x + (b << 18);
    const float* offb = offset + b * (2 * KK_ * PLANE_) + pix;
    const float* mb   = mask   + b * (KK_ * PLANE_)    + pix;

    float w0[KK_], w1[KK_], w2[KK_];
    #pragma unroll
    for (int k = 0; k < KK_; ++k) {
        w0[k] = weight[0 * KK_ + k];
        w1[k] = weight[1 * KK_ + k];
        w2[k] = weight[2 * KK_ + k];
    }
    const float b0 = bias[0], b1 = bias[1], b2 = bias[2];
    const float fho = (float)ho, fwo = (float)wo0;

    float a00 = 0.f, a01 = 0.f, a10 = 0.f, a11 = 0.f, a20 = 0.f, a21 = 0.f;

    #pragma unroll
    for (int kh = 0; kh < 3; ++kh) {
        #pragma unroll
        for (int kw = 0; kw < 3; ++kw) {
            const int kk = kh * 3 + kw;
            const f2 dy2 = *(const f2*)(offb + (2 * kk)     * PLANE_);
            const f2 dx2 = *(const f2*)(offb + (2 * kk + 1) * PLANE_);
            const f2 m2  = *(const f2*)(mb   +  kk          * PLANE_);
            #pragma unroll
            for (int p = 0; p < 2; ++p) {
                const float py = (fho + (float)kh) + dy2[p];
                const float px = (fwo + (float)(kw + p)) + dx2[p];
                const float y0f = floorf(py), x0f = floorf(px);
                const float ly = py - y0f, lx = px - x0f;
                const float y1f = y0f + 1.0f, x1f = x0f + 1.0f;
                const float vy0 = (y0f >= 0.f && y0f <= 511.f) ? 1.f : 0.f;
                const float vy1 = (y1f >= 0.f && y1f <= 511.f) ? 1.f : 0.f;
                const float vx0 = (x0f >= 0.f && x0f <= 511.f) ? 1.f : 0.f;
                const float vx1 = (x1f >= 0.f && x1f <= 511.f) ? 1.f : 0.f;
                const int yi0 = iclamp((int)y0f, 0, 511);
                const int yi1 = iclamp((int)y1f, 0, 511);
                const int xi0 = iclamp((int)x0f, 0, 511);
                const int xi1 = iclamp((int)x1f, 0, 511);
                const float v00 = xb[(yi0 << 9) + xi0] * (vy0 * vx0);
                const float v01 = xb[(yi0 << 9) + xi1] * (vy0 * vx1);
                const float v10 = xb[(yi1 << 9) + xi0] * (vy1 * vx0);
                const float v11 = xb[(yi1 << 9) + xi1] * (vy1 * vx1);
                const float top = fmaf(lx, v01 - v00, v00);
                const float bot = fmaf(lx, v11 - v10, v10);
                const float val = fmaf(ly, bot - top, top);
                const float s   = val * m2[p];
                if (p == 0) { a00 = fmaf(w0[kk], s, a00); a10 = fmaf(w1[kk], s, a10); a20 = fmaf(w2[kk], s, a20); }
                else        { a01 = fmaf(w0[kk], s, a01); a11 = fmaf(w1[kk], s, a11); a21 = fmaf(w2[kk], s, a21); }
            }
        }
    }
    const int ob = b * (COUT_ * PLANE_) + pix;
    f2 o0 = {a00 + b0, a01 + b0};
    f2 o1 = {a10 + b1, a11 + b1};
    f2 o2 = {a20 + b2, a21 + b2};
    *(f2*)(out + ob)              = o0;
    *(f2*)(out + ob + PLANE_)     = o1;
    *(f2*)(out + ob + 2 * PLANE_) = o2;
}

extern "C" void kernel_launch(void* const* d_in, const int* in_sizes, int n_in,
                              void* d_out, int out_size, void* d_ws, size_t ws_size,
                              hipStream_t stream) {
    const float* x      = (const float*)d_in[0];
    const float* offset = (const float*)d_in[1];
    const float* mask   = (const float*)d_in[2];
    const float* weight = (const float*)d_in[3];
    const float* bias   = (const float*)d_in[4];
    float* out = (float*)d_out;

    const size_t p_bytes = (size_t)B_ * 512 * 512 * sizeof(f2);   // 16 MiB

    if (ws_size >= p_bytes) {
        f2* P = (f2*)d_ws;
        pack_pairs<<<(B_ * 512 * 512) / 256, 256, 0, stream>>>(x, P);
        dcn_fwd_pair<<<B_ * HO_, 256, 0, stream>>>(x, P, offset, mask, weight, bias, out);
    } else {
        dcn_fwd_direct<<<B_ * HO_, 256, 0, stream>>>(x, offset, mask, weight, bias, out);
    }
}

// Round 13
// 409.634 us; speedup vs baseline: 1.1080x; 1.1080x over previous
//
#include <hip/hip_runtime.h>

// Problem constants
#define B_    8
#define H_    512
#define W_    512
#define KK_   9
#define COUT_ 3
#define HO_   510
#define WO_   510
#define PLANE_ 260100           // HO_*WO_

typedef float f2 __attribute__((ext_vector_type(2)));

__device__ __forceinline__ int iclamp(int v, int lo, int hi) {
    return v < lo ? lo : (v > hi ? hi : v);
}

// ---------- pre-pass: pack vertical row pairs ----------
// P[b][y][x] = { x[y][x], x[min(y+1,511)][x] }  (float2, 16 MiB total)
__global__ __launch_bounds__(256) void pack_pairs(
    const float* __restrict__ x, f2* __restrict__ P)
{
    const int i  = blockIdx.x * 256 + threadIdx.x;   // 8*512*512
    const int xi = i & 511;
    const int y  = (i >> 9) & 511;
    const int b  = i >> 18;
    const float* xb = x + (b << 18);
    const int y1 = y < 511 ? y + 1 : 511;
    f2 q;
    q[0] = xb[(y  << 9) + xi];
    q[1] = xb[(y1 << 9) + xi];
    P[i] = q;
}

// ---------- main kernel: two 8B gathers per bilinear sample ----------
__global__ __launch_bounds__(256, 6) void dcn_fwd_pair(
    const float* __restrict__ x,       // slow path only
    const f2*    __restrict__ P,       // [B,512,512] row pairs
    const float* __restrict__ offset,  // [B,18,510,510]
    const float* __restrict__ mask,    // [B,9,510,510]
    const float* __restrict__ weight,  // [3,1,3,3]
    const float* __restrict__ bias,    // [3]
    float* __restrict__ out)           // [B,3,510,510]
{
    // Sequential mapping (R10-proven): consecutive blocks = consecutive rows
    // of the same batch -> stream reads, table reads, and stores all stay local.
    const int bid = blockIdx.x;        // 0 .. 8*510-1
    const int ho  = bid % HO_;
    const int b   = bid / HO_;

    const int j   = threadIdx.x;       // 2 px each
    int wo0 = 2 * j;
    if (wo0 > WO_ - 2) wo0 = WO_ - 2;  // j=255 duplicates last pair (benign)

    const int pix = ho * WO_ + wo0;
    const float* xb = x + (b << 18);
    const f2*    Pb = P + (b << 18);
    const float* offb = offset + b * (2 * KK_ * PLANE_) + pix;
    const float* mb   = mask   + b * (KK_ * PLANE_)    + pix;

    float w0[KK_], w1[KK_], w2[KK_];
    #pragma unroll
    for (int k = 0; k < KK_; ++k) {
        w0[k] = weight[0 * KK_ + k];
        w1[k] = weight[1 * KK_ + k];
        w2[k] = weight[2 * KK_ + k];
    }
    const float b0 = bias[0], b1 = bias[1], b2 = bias[2];

    const float fho = (float)ho;
    const float fwo = (float)wo0;

    float a00 = 0.f, a01 = 0.f;
    float a10 = 0.f, a11 = 0.f;
    float a20 = 0.f, a21 = 0.f;

    #pragma unroll
    for (int kh = 0; kh < 3; ++kh) {
        #pragma unroll
        for (int kw = 0; kw < 3; ++kw) {
            const int kk = kh * 3 + kw;
            const f2 dy2 = *(const f2*)(offb + (2 * kk)     * PLANE_);
            const f2 dx2 = *(const f2*)(offb + (2 * kk + 1) * PLANE_);
            const f2 m2  = *(const f2*)(mb   +  kk          * PLANE_);

            #pragma unroll
            for (int p = 0; p < 2; ++p) {
                const float py = (fho + (float)kh) + dy2[p];
                const float px = (fwo + (float)(kw + p)) + dx2[p];

                const float y0f = floorf(py);
                const float x0f = floorf(px);
                const float ly  = py - y0f;
                const float lx  = px - x0f;

                const int iy0 = (int)y0f;
                const int ix0 = (int)x0f;

                float v00, v01, v10, v11;
                if (__builtin_expect(((unsigned)iy0 < 511u) & ((unsigned)ix0 < 511u), 1)) {
                    // all 4 corners in-image: two 8B gathers, no validity math
                    const int a = (iy0 << 9) + ix0;
                    const f2 q0 = Pb[a];        // {v00, v10}
                    const f2 q1 = Pb[a + 1];    // {v01, v11}
                    v00 = q0[0]; v10 = q0[1];
                    v01 = q1[0]; v11 = q1[1];
                } else {
                    // border/outside: full reference semantics (rare)
                    const float y1f = y0f + 1.0f, x1f = x0f + 1.0f;
                    const float vy0 = (y0f >= 0.f && y0f <= 511.f) ? 1.f : 0.f;
                    const float vy1 = (y1f >= 0.f && y1f <= 511.f) ? 1.f : 0.f;
                    const float vx0 = (x0f >= 0.f && x0f <= 511.f) ? 1.f : 0.f;
                    const float vx1 = (x1f >= 0.f && x1f <= 511.f) ? 1.f : 0.f;
                    const int yi0 = iclamp(iy0, 0, 511);
                    const int yi1 = iclamp(iy0 + 1, 0, 511);
                    const int xi0 = iclamp(ix0, 0, 511);
                    const int xi1 = iclamp(ix0 + 1, 0, 511);
                    v00 = xb[(yi0 << 9) + xi0] * (vy0 * vx0);
                    v01 = xb[(yi0 << 9) + xi1] * (vy0 * vx1);
                    v10 = xb[(yi1 << 9) + xi0] * (vy1 * vx0);
                    v11 = xb[(yi1 << 9) + xi1] * (vy1 * vx1);
                }

                const float top = fmaf(lx, v01 - v00, v00);
                const float bot = fmaf(lx, v11 - v10, v10);
                const float val = fmaf(ly, bot - top, top);
                const float s   = val * m2[p];

                if (p == 0) {
                    a00 = fmaf(w0[kk], s, a00);
                    a10 = fmaf(w1[kk], s, a10);
                    a20 = fmaf(w2[kk], s, a20);
                } else {
                    a01 = fmaf(w0[kk], s, a01);
                    a11 = fmaf(w1[kk], s, a11);
                    a21 = fmaf(w2[kk], s, a21);
                }
            }
        }
    }

    const int ob = b * (COUT_ * PLANE_) + pix;
    f2 o0 = {a00 + b0, a01 + b0};
    f2 o1 = {a10 + b1, a11 + b1};
    f2 o2 = {a20 + b2, a21 + b2};
    *(f2*)(out + ob)              = o0;
    *(f2*)(out + ob + PLANE_)     = o1;
    *(f2*)(out + ob + 2 * PLANE_) = o2;
}

// ---------- fallback (no workspace): R5-style direct-gather kernel ----------
__global__ __launch_bounds__(256) void dcn_fwd_direct(
    const float* __restrict__ x, const float* __restrict__ offset,
    const float* __restrict__ mask, const float* __restrict__ weight,
    const float* __restrict__ bias, float* __restrict__ out)
{
    const int bid = blockIdx.x;
    const int ho  = bid % HO_;
    const int b   = bid / HO_;
    const int j   = threadIdx.x;
    int wo0 = 2 * j;
    if (wo0 > WO_ - 2) wo0 = WO_ - 2;

    const int pix = ho * WO_ + wo0;
    const float* xb   = x + (b << 18);
    const float* offb = offset + b * (2 * KK_ * PLANE_) + pix;
    const float* mb   = mask   + b * (KK_ * PLANE_)    + pix;

    float w0[KK_], w1[KK_], w2[KK_];
    #pragma unroll
    for (int k = 0; k < KK_; ++k) {
        w0[k] = weight[0 * KK_ + k];
        w1[k] = weight[1 * KK_ + k];
        w2[k] = weight[2 * KK_ + k];
    }
    const float b0 = bias[0], b1 = bias[1], b2 = bias[2];
    const float fho = (float)ho, fwo = (float)wo0;

    float a00 = 0.f, a01 = 0.f, a10 = 0.f, a11 = 0.f, a20 = 0.f, a21 = 0.f;

    #pragma unroll
    for (int kh = 0; kh < 3; ++kh) {
        #pragma unroll
        for (int kw = 0; kw < 3; ++kw) {
            const int kk = kh * 3 + kw;
            const f2 dy2 = *(const f2*)(offb + (2 * kk)     * PLANE_);
            const f2 dx2 = *(const f2*)(offb + (2 * kk + 1) * PLANE_);
            const f2 m2  = *(const f2*)(mb   +  kk          * PLANE_);
            #pragma unroll
            for (int p = 0; p < 2; ++p) {
                const float py = (fho + (float)kh) + dy2[p];
                const float px = (fwo + (float)(kw + p)) + dx2[p];
                const float y0f = floorf(py), x0f = floorf(px);
                const float ly = py - y0f, lx = px - x0f;
                const float y1f = y0f + 1.0f, x1f = x0f + 1.0f;
                const float vy0 = (y0f >= 0.f && y0f <= 511.f) ? 1.f : 0.f;
                const float vy1 = (y1f >= 0.f && y1f <= 511.f) ? 1.f : 0.f;
                const float vx0 = (x0f >= 0.f && x0f <= 511.f) ? 1.f : 0.f;
                const float vx1 = (x1f >= 0.f && x1f <= 511.f) ? 1.f : 0.f;
                const int yi0 = iclamp((int)y0f, 0, 511);
                const int yi1 = iclamp((int)y1f, 0, 511);
                const int xi0 = iclamp((int)x0f, 0, 511);
                const int xi1 = iclamp((int)x1f, 0, 511);
                const float v00 = xb[(yi0 << 9) + xi0] * (vy0 * vx0);
                const float v01 = xb[(yi0 << 9) + xi1] * (vy0 * vx1);
                const float v10 = xb[(yi1 << 9) + xi0] * (vy1 * vx0);
                const float v11 = xb[(yi1 << 9) + xi1] * (vy1 * vx1);
                const float top = fmaf(lx, v01 - v00, v00);
                const float bot = fmaf(lx, v11 - v10, v10);
                const float val = fmaf(ly, bot - top, top);
                const float s   = val * m2[p];
                if (p == 0) { a00 = fmaf(w0[kk], s, a00); a10 = fmaf(w1[kk], s, a10); a20 = fmaf(w2[kk], s, a20); }
                else        { a01 = fmaf(w0[kk], s, a01); a11 = fmaf(w1[kk], s, a11); a21 = fmaf(w2[kk], s, a21); }
            }
        }
    }
    const int ob = b * (COUT_ * PLANE_) + pix;
    f2 o0 = {a00 + b0, a01 + b0};
    f2 o1 = {a10 + b1, a11 + b1};
    f2 o2 = {a20 + b2, a21 + b2};
    *(f2*)(out + ob)              = o0;
    *(f2*)(out + ob + PLANE_)     = o1;
    *(f2*)(out + ob + 2 * PLANE_) = o2;
}

extern "C" void kernel_launch(void* const* d_in, const int* in_sizes, int n_in,
                              void* d_out, int out_size, void* d_ws, size_t ws_size,
                              hipStream_t stream) {
    const float* x      = (const float*)d_in[0];
    const float* offset = (const float*)d_in[1];
    const float* mask   = (const float*)d_in[2];
    const float* weight = (const float*)d_in[3];
    const float* bias   = (const float*)d_in[4];
    float* out = (float*)d_out;

    const size_t p_bytes = (size_t)B_ * 512 * 512 * sizeof(f2);   // 16 MiB

    if (ws_size >= p_bytes) {
        f2* P = (f2*)d_ws;
        pack_pairs<<<(B_ * 512 * 512) / 256, 256, 0, stream>>>(x, P);
        dcn_fwd_pair<<<B_ * HO_, 256, 0, stream>>>(x, P, offset, mask, weight, bias, out);
    } else {
        dcn_fwd_direct<<<B_ * HO_, 256, 0, stream>>>(x, offset, mask, weight, bias, out);
    }
}

// Round 14
// 65.553 us; speedup vs baseline: 6.9239x; 6.2489x over previous
//
#include <hip/hip_runtime.h>

// Problem constants
#define B_    8
#define H_    512
#define W_    512
#define KK_   9
#define COUT_ 3
#define HO_   510
#define WO_   510
#define PLANE_ 260100           // HO_*WO_

__device__ __forceinline__ int iclamp(int v, int lo, int hi) {
    return v < lo ? lo : (v > hi ? hi : v);
}

// Wave = 4x16 output patch (lane: r = lane>>4, c = lane&15).
// Block = 512 threads = 8 waves side-by-side = 4 rows x 128 cols.
// Rationale: clusters each gather wave-instr's lanes into a ~8-row x ~20-col
// x-footprint (~16-24 cache lines) instead of 1-row x ~128-col (~30-45 lines);
// TA walks distinct lines per instr, so fewer lines = fewer cycles.
__global__ __launch_bounds__(512, 4) void dcn_fwd_kernel(
    const float* __restrict__ x,       // [B,1,512,512]
    const float* __restrict__ offset,  // [B,18,510,510]
    const float* __restrict__ mask,    // [B,9,510,510]
    const float* __restrict__ weight,  // [3,1,3,3]
    const float* __restrict__ bias,    // [3]
    float* __restrict__ out)           // [B,3,510,510]
{
    const int bid  = blockIdx.x;       // 4 colblk * 128 band * 8 batch = 4096
    const int wt   = bid & 3;          // col-block 0..3 (128 cols each)
    const int band = (bid >> 2) & 127; // row band 0..127 (4 rows each)
    const int b    = bid >> 9;         // batch

    const int tid  = threadIdx.x;
    const int wave = tid >> 6;         // 0..7
    const int lane = tid & 63;
    const int r    = lane >> 4;        // 0..3
    const int c    = lane & 15;        // 0..15

    const int ho = band * 4 + r;               // 0..511 (510,511 invalid)
    const int wo = wt * 128 + wave * 16 + c;   // 0..511 (510,511 invalid)
    const bool valid = (ho < HO_) & (wo < WO_);
    const int ho_c = ho < HO_ ? ho : HO_ - 1;  // clamped for safe loads
    const int wo_c = wo < WO_ ? wo : WO_ - 1;

    const int pix = ho_c * WO_ + wo_c;
    const float* xb   = x + (b << 18);
    const float* offb = offset + b * (2 * KK_ * PLANE_) + pix;
    const float* mb   = mask   + b * (KK_ * PLANE_)    + pix;

    // weights/bias: uniform addresses -> scalar broadcast loads
    float w0[KK_], w1[KK_], w2[KK_];
    #pragma unroll
    for (int k = 0; k < KK_; ++k) {
        w0[k] = weight[0 * KK_ + k];
        w1[k] = weight[1 * KK_ + k];
        w2[k] = weight[2 * KK_ + k];
    }
    const float b0 = bias[0], b1 = bias[1], b2 = bias[2];

    const float fho = (float)ho_c;
    const float fwo = (float)wo_c;

    float acc0 = 0.f, acc1 = 0.f, acc2 = 0.f;

    #pragma unroll
    for (int kh = 0; kh < 3; ++kh) {
        #pragma unroll
        for (int kw = 0; kw < 3; ++kw) {
            const int kk = kh * 3 + kw;
            const float dy = offb[(2 * kk)     * PLANE_];
            const float dx = offb[(2 * kk + 1) * PLANE_];
            const float m  = mb  [ kk          * PLANE_];

            const float py = (fho + (float)kh) + dy;
            const float px = (fwo + (float)kw) + dx;

            const float y0f = floorf(py);
            const float x0f = floorf(px);
            const float ly  = py - y0f;
            const float lx  = px - x0f;
            const float y1f = y0f + 1.0f;
            const float x1f = x0f + 1.0f;

            // validity on UNCLIPPED float corner coords (reference semantics)
            const float vy0 = (y0f >= 0.f && y0f <= 511.f) ? 1.f : 0.f;
            const float vy1 = (y1f >= 0.f && y1f <= 511.f) ? 1.f : 0.f;
            const float vx0 = (x0f >= 0.f && x0f <= 511.f) ? 1.f : 0.f;
            const float vx1 = (x1f >= 0.f && x1f <= 511.f) ? 1.f : 0.f;

            const int yi0 = iclamp((int)y0f, 0, 511);
            const int yi1 = iclamp((int)y1f, 0, 511);
            const int xi0 = iclamp((int)x0f, 0, 511);
            const int xi1 = iclamp((int)x1f, 0, 511);

            const float v00 = xb[(yi0 << 9) + xi0] * (vy0 * vx0);
            const float v01 = xb[(yi0 << 9) + xi1] * (vy0 * vx1);
            const float v10 = xb[(yi1 << 9) + xi0] * (vy1 * vx0);
            const float v11 = xb[(yi1 << 9) + xi1] * (vy1 * vx1);

            const float top = fmaf(lx, v01 - v00, v00);
            const float bot = fmaf(lx, v11 - v10, v10);
            const float val = fmaf(ly, bot - top, top);
            const float s   = val * m;
            acc0 = fmaf(w0[kk], s, acc0);
            acc1 = fmaf(w1[kk], s, acc1);
            acc2 = fmaf(w2[kk], s, acc2);
        }
    }

    if (valid) {
        const int ob = b * (COUT_ * PLANE_) + pix;
        out[ob]              = acc0 + b0;
        out[ob + PLANE_]     = acc1 + b1;
        out[ob + 2 * PLANE_] = acc2 + b2;
    }
}

extern "C" void kernel_launch(void* const* d_in, const int* in_sizes, int n_in,
                              void* d_out, int out_size, void* d_ws, size_t ws_size,
                              hipStream_t stream) {
    const float* x      = (const float*)d_in[0];
    const float* offset = (const float*)d_in[1];
    const float* mask   = (const float*)d_in[2];
    const float* weight = (const float*)d_in[3];
    const float* bias   = (const float*)d_in[4];
    float* out = (float*)d_out;

    const int grid = 4 * 128 * B_;   // colblk x band x batch = 4096
    dcn_fwd_kernel<<<grid, 512, 0, stream>>>(x, offset, mask, weight, bias, out);
}